// Round 1
// baseline (191.033 us; speedup 1.0000x reference)
//
#include <hip/hip_runtime.h>
#include <math.h>

#define NXC 200   // grid edge
#define NBB 512   // batch

// One block per batch. Wave w (of 4) owns rows i = w + 4r, r=0..49.
// Lane l<50 loads float4 covering columns 4l..4l+3 of each owned row.
// Accumulates: column sums (register, per-lane), row sums (wave shuffle),
// boundary rows 0/1/198/199 and cols 0/1/198/199 of heat into LDS.
// Epilogue: closed-form vertical/horizontal diffs, per-batch min/max,
// OHEM-weighted partial sum, one atomicAdd to the scalar output.
__global__ __launch_bounds__(256, 1) void heat_loss_kernel(
    const float* __restrict__ layout, const float* __restrict__ heat,
    float* __restrict__ out) {
  const int b    = blockIdx.x;
  const int tid  = threadIdx.x;
  const int wave = tid >> 6;
  const int lane = tid & 63;

  const float4* __restrict__ hp =
      reinterpret_cast<const float4*>(heat + (size_t)b * NXC * NXC);
  const float4* __restrict__ lp =
      reinterpret_cast<const float4*>(layout + (size_t)b * NXC * NXC);

  __shared__ float s_hcs[4][NXC];   // per-wave column-sum partials (heat)
  __shared__ float s_lcs[4][NXC];   // per-wave column-sum partials (layout)
  __shared__ float s_hrs[NXC];      // row sums heat
  __shared__ float s_lrs[NXC];      // row sums layout
  __shared__ float s_brow[4][NXC];  // heat rows 0,1,198,199
  __shared__ float s_bcol[4][NXC];  // heat cols 0,1,198,199
  __shared__ float s_CS[NXC];       // total column sums heat
  __shared__ float s_CL[NXC];       // total column sums layout
  __shared__ float s_red[32];

  float hc0=0.f,hc1=0.f,hc2=0.f,hc3=0.f;
  float lc0=0.f,lc1=0.f,lc2=0.f,lc3=0.f;

  const bool active = (lane < 50);

  for (int r = 0; r < 50; ++r) {
    const int i = wave + 4 * r;
    float4 hv = make_float4(0.f,0.f,0.f,0.f);
    float4 lv = make_float4(0.f,0.f,0.f,0.f);
    if (active) {
      hv = hp[i * 50 + lane];
      lv = lp[i * 50 + lane];
    }
    hc0 += hv.x; hc1 += hv.y; hc2 += hv.z; hc3 += hv.w;
    lc0 += lv.x; lc1 += lv.y; lc2 += lv.z; lc3 += lv.w;

    if (active) {
      int bi = -1;
      if (i == 0) bi = 0; else if (i == 1) bi = 1;
      else if (i == NXC-2) bi = 2; else if (i == NXC-1) bi = 3;
      if (bi >= 0) {
        s_brow[bi][4*lane+0] = hv.x; s_brow[bi][4*lane+1] = hv.y;
        s_brow[bi][4*lane+2] = hv.z; s_brow[bi][4*lane+3] = hv.w;
      }
      if (lane == 0)  { s_bcol[0][i] = hv.x; s_bcol[1][i] = hv.y; }  // j=0,1
      if (lane == 49) { s_bcol[2][i] = hv.z; s_bcol[3][i] = hv.w; }  // j=198,199
    }

    float hs = (hv.x + hv.y) + (hv.z + hv.w);
    float ls = (lv.x + lv.y) + (lv.z + lv.w);
    #pragma unroll
    for (int off = 32; off > 0; off >>= 1) {
      hs += __shfl_down(hs, off);
      ls += __shfl_down(ls, off);
    }
    if (lane == 0) { s_hrs[i] = hs; s_lrs[i] = ls; }
  }

  if (active) {
    s_hcs[wave][4*lane+0] = hc0; s_hcs[wave][4*lane+1] = hc1;
    s_hcs[wave][4*lane+2] = hc2; s_hcs[wave][4*lane+3] = hc3;
    s_lcs[wave][4*lane+0] = lc0; s_lcs[wave][4*lane+1] = lc1;
    s_lcs[wave][4*lane+2] = lc2; s_lcs[wave][4*lane+3] = lc3;
  }
  __syncthreads();

  if (tid < NXC) {
    s_CS[tid] = (s_hcs[0][tid] + s_hcs[1][tid]) + (s_hcs[2][tid] + s_hcs[3][tid]);
    s_CL[tid] = (s_lcs[0][tid] + s_lcs[1][tid]) + (s_lcs[2][tid] + s_lcs[3][tid]);
  }
  __syncthreads();

  const float COF = (float)(0.25 * (0.1/199.0) * (0.1/199.0));
  float dv = 0.f, dh = 0.f;
  if (tid < NXC) {
    const int j  = tid;
    const int jm = (j == 0) ? 1 : j - 1;
    const int jp = (j == NXC-1) ? NXC-2 : j + 1;
    // Sum over rows of x[:, j]:
    float Sv = 0.25f * (2.f*s_CS[j]
                        + s_brow[1][j] - s_brow[3][j]     // +h[1,j] - h[199,j]
                        + s_brow[2][j] - s_brow[0][j]     // +h[198,j] - h[0,j]
                        + s_CS[jm] + s_CS[jp])
             + COF * s_CL[j];
    dv = fabsf(Sv - s_CS[j]) * (1.f / NXC);
    // Sum over cols of x[i, :]:
    float Sh = 0.25f * (2.f*s_hrs[j]
                        + s_bcol[1][j] - s_bcol[3][j]     // +h[i,1] - h[i,199]
                        + s_bcol[2][j] - s_bcol[0][j]     // +h[i,198] - h[i,0]
                        + s_hrs[jm] + s_hrs[jp])
             + COF * s_lrs[j];
    dh = fabsf(Sh - s_hrs[j]) * (1.f / NXC);
  }

  // per-batch min/max of dv and dh (dv,dh >= 0 so max pad 0 is safe)
  float mnv = (tid < NXC) ? dv : INFINITY;
  float mxv = dv;
  float mnh = (tid < NXC) ? dh : INFINITY;
  float mxh = dh;
  #pragma unroll
  for (int off = 32; off > 0; off >>= 1) {
    mnv = fminf(mnv, __shfl_down(mnv, off));
    mxv = fmaxf(mxv, __shfl_down(mxv, off));
    mnh = fminf(mnh, __shfl_down(mnh, off));
    mxh = fmaxf(mxh, __shfl_down(mxh, off));
  }
  if (lane == 0) {
    s_red[wave]      = mnv;
    s_red[4 + wave]  = mxv;
    s_red[8 + wave]  = mnh;
    s_red[12 + wave] = mxh;
  }
  __syncthreads();
  const float MNV = fminf(fminf(s_red[0],  s_red[1]),  fminf(s_red[2],  s_red[3]));
  const float MXV = fmaxf(fmaxf(s_red[4],  s_red[5]),  fmaxf(s_red[6],  s_red[7]));
  const float MNH = fminf(fminf(s_red[8],  s_red[9]),  fminf(s_red[10], s_red[11]));
  const float MXH = fmaxf(fmaxf(s_red[12], s_red[13]), fmaxf(s_red[14], s_red[15]));

  float contrib = 0.f;
  if (tid < NXC) {
    contrib = 10.f * (dv - MNV) * dv / (MXV - MNV)
            + 10.f * (dh - MNH) * dh / (MXH - MNH);
  }
  #pragma unroll
  for (int off = 32; off > 0; off >>= 1) contrib += __shfl_down(contrib, off);
  if (lane == 0) s_red[16 + wave] = contrib;
  __syncthreads();
  if (tid == 0) {
    const float tot = (s_red[16] + s_red[17]) + (s_red[18] + s_red[19]);
    atomicAdd(out, tot * (1.f / ((float)NBB * (float)NXC)));
  }
}

extern "C" void kernel_launch(void* const* d_in, const int* in_sizes, int n_in,
                              void* d_out, int out_size, void* d_ws, size_t ws_size,
                              hipStream_t stream) {
  const float* layout = (const float*)d_in[0];
  const float* heat   = (const float*)d_in[1];
  float* out = (float*)d_out;

  // d_out is poisoned to 0xAA before every timed launch — zero it first.
  hipMemsetAsync(out, 0, (size_t)out_size * sizeof(float), stream);
  heat_loss_kernel<<<NBB, 256, 0, stream>>>(layout, heat, out);
}

// Round 2
// 187.286 us; speedup vs baseline: 1.0200x; 1.0200x over previous
//
#include <hip/hip_runtime.h>
#include <math.h>

#define NXC 200   // grid edge
#define NBB 512   // batch
#define NW  16    // waves per block (1024 threads)

// One block (1024 threads = 16 waves) per batch. Wave w owns rows
// i = w + 16k (k=0..12, guarded i<200). Lane l<50 loads float4 covering
// columns 4l..4l+3. Column sums accumulate per-lane in registers; row sums
// reduce via wave shuffle each iteration (chain is only 13 iters/wave now).
// 2 blocks/CU x 16 waves = 32 waves/CU for latency hiding.
__global__ __launch_bounds__(1024, 1) void heat_loss_kernel(
    const float* __restrict__ layout, const float* __restrict__ heat,
    float* __restrict__ out) {
  const int b    = blockIdx.x;
  const int tid  = threadIdx.x;
  const int wave = tid >> 6;
  const int lane = tid & 63;

  const float4* __restrict__ hp =
      reinterpret_cast<const float4*>(heat + (size_t)b * NXC * NXC);
  const float4* __restrict__ lp =
      reinterpret_cast<const float4*>(layout + (size_t)b * NXC * NXC);

  __shared__ float s_hcs[NW][NXC];  // per-wave column-sum partials (heat)
  __shared__ float s_lcs[NW][NXC];  // per-wave column-sum partials (layout)
  __shared__ float s_hrs[NXC];      // row sums heat
  __shared__ float s_lrs[NXC];      // row sums layout
  __shared__ float s_brow[4][NXC];  // heat rows 0,1,198,199
  __shared__ float s_bcol[4][NXC];  // heat cols 0,1,198,199
  __shared__ float s_CS[NXC];       // total column sums heat
  __shared__ float s_CL[NXC];       // total column sums layout
  __shared__ float s_red[4][NW];    // minv/maxv/minh/maxh per wave
  __shared__ float s_sum[NW];       // contrib partial per wave

  float hc0=0.f,hc1=0.f,hc2=0.f,hc3=0.f;
  float lc0=0.f,lc1=0.f,lc2=0.f,lc3=0.f;

  const bool act = (lane < 50);

  #pragma unroll
  for (int k = 0; k < 13; ++k) {
    const int i = wave + NW * k;          // wave-uniform
    if (i < NXC) {
      float4 hv = make_float4(0.f,0.f,0.f,0.f);
      float4 lv = make_float4(0.f,0.f,0.f,0.f);
      if (act) {
        hv = hp[i * 50 + lane];
        lv = lp[i * 50 + lane];
      }
      hc0 += hv.x; hc1 += hv.y; hc2 += hv.z; hc3 += hv.w;
      lc0 += lv.x; lc1 += lv.y; lc2 += lv.z; lc3 += lv.w;

      if (act) {
        if (i <= 1 || i >= NXC - 2) {
          const int bi = (i <= 1) ? i : i - (NXC - 4);  // 0,1,198->2,199->3
          s_brow[bi][4*lane+0] = hv.x; s_brow[bi][4*lane+1] = hv.y;
          s_brow[bi][4*lane+2] = hv.z; s_brow[bi][4*lane+3] = hv.w;
        }
        if (lane == 0)  { s_bcol[0][i] = hv.x; s_bcol[1][i] = hv.y; }  // j=0,1
        if (lane == 49) { s_bcol[2][i] = hv.z; s_bcol[3][i] = hv.w; }  // j=198,199
      }

      float hs = (hv.x + hv.y) + (hv.z + hv.w);
      float ls = (lv.x + lv.y) + (lv.z + lv.w);
      #pragma unroll
      for (int off = 32; off > 0; off >>= 1) {
        hs += __shfl_down(hs, off);
        ls += __shfl_down(ls, off);
      }
      if (lane == 0) { s_hrs[i] = hs; s_lrs[i] = ls; }
    }
  }

  if (act) {
    s_hcs[wave][4*lane+0] = hc0; s_hcs[wave][4*lane+1] = hc1;
    s_hcs[wave][4*lane+2] = hc2; s_hcs[wave][4*lane+3] = hc3;
    s_lcs[wave][4*lane+0] = lc0; s_lcs[wave][4*lane+1] = lc1;
    s_lcs[wave][4*lane+2] = lc2; s_lcs[wave][4*lane+3] = lc3;
  }
  __syncthreads();

  if (tid < NXC) {
    float a = 0.f, c = 0.f;
    #pragma unroll
    for (int w = 0; w < NW; ++w) { a += s_hcs[w][tid]; c += s_lcs[w][tid]; }
    s_CS[tid] = a; s_CL[tid] = c;
  }
  __syncthreads();

  const float COF = (float)(0.25 * (0.1/199.0) * (0.1/199.0));
  float dv = 0.f, dh = 0.f;
  if (tid < NXC) {
    const int j  = tid;
    const int jm = (j == 0) ? 1 : j - 1;
    const int jp = (j == NXC-1) ? NXC-2 : j + 1;
    float Sv = 0.25f * (2.f*s_CS[j]
                        + s_brow[1][j] - s_brow[3][j]     // +h[1,j] - h[199,j]
                        + s_brow[2][j] - s_brow[0][j]     // +h[198,j] - h[0,j]
                        + s_CS[jm] + s_CS[jp])
             + COF * s_CL[j];
    dv = fabsf(Sv - s_CS[j]) * (1.f / NXC);
    float Sh = 0.25f * (2.f*s_hrs[j]
                        + s_bcol[1][j] - s_bcol[3][j]     // +h[i,1] - h[i,199]
                        + s_bcol[2][j] - s_bcol[0][j]     // +h[i,198] - h[i,0]
                        + s_hrs[jm] + s_hrs[jp])
             + COF * s_lrs[j];
    dh = fabsf(Sh - s_hrs[j]) * (1.f / NXC);
  }

  // per-batch min/max of dv and dh (dv,dh >= 0 so max pad 0 is safe)
  float mnv = (tid < NXC) ? dv : INFINITY;
  float mxv = dv;
  float mnh = (tid < NXC) ? dh : INFINITY;
  float mxh = dh;
  #pragma unroll
  for (int off = 32; off > 0; off >>= 1) {
    mnv = fminf(mnv, __shfl_down(mnv, off));
    mxv = fmaxf(mxv, __shfl_down(mxv, off));
    mnh = fminf(mnh, __shfl_down(mnh, off));
    mxh = fmaxf(mxh, __shfl_down(mxh, off));
  }
  if (lane == 0) {
    s_red[0][wave] = mnv;
    s_red[1][wave] = mxv;
    s_red[2][wave] = mnh;
    s_red[3][wave] = mxh;
  }
  __syncthreads();

  float MNV = INFINITY, MXV = -INFINITY, MNH = INFINITY, MXH = -INFINITY;
  #pragma unroll
  for (int w = 0; w < NW; ++w) {
    MNV = fminf(MNV, s_red[0][w]); MXV = fmaxf(MXV, s_red[1][w]);
    MNH = fminf(MNH, s_red[2][w]); MXH = fmaxf(MXH, s_red[3][w]);
  }

  float contrib = 0.f;
  if (tid < NXC) {
    contrib = 10.f * (dv - MNV) * dv / (MXV - MNV)
            + 10.f * (dh - MNH) * dh / (MXH - MNH);
  }
  #pragma unroll
  for (int off = 32; off > 0; off >>= 1) contrib += __shfl_down(contrib, off);
  if (lane == 0) s_sum[wave] = contrib;
  __syncthreads();
  if (tid == 0) {
    float tot = 0.f;
    #pragma unroll
    for (int w = 0; w < NW; ++w) tot += s_sum[w];
    atomicAdd(out, tot * (1.f / ((float)NBB * (float)NXC)));
  }
}

extern "C" void kernel_launch(void* const* d_in, const int* in_sizes, int n_in,
                              void* d_out, int out_size, void* d_ws, size_t ws_size,
                              hipStream_t stream) {
  const float* layout = (const float*)d_in[0];
  const float* heat   = (const float*)d_in[1];
  float* out = (float*)d_out;

  // d_out is poisoned to 0xAA before every timed launch — zero it first.
  hipMemsetAsync(out, 0, (size_t)out_size * sizeof(float), stream);
  heat_loss_kernel<<<NBB, 1024, 0, stream>>>(layout, heat, out);
}